// Round 7
// baseline (93.949 us; speedup 1.0000x reference)
//
#include <hip/hip_runtime.h>
#include <cmath>

#define TPB   128                 // threads per block (2 waves); each thread owns 4 cols
#define TH    8                   // output rows per block tile (14 input rows = 2*7)
#define WID   512
#define HEI   512
#define NIMG  64
#define NTILE (HEI / TH)          // 64
#define NBLK  (NIMG * NTILE)      // 4096

// R4 lesson: f32 ring overflowed into AGPRs -> ~200 regs -> 2 waves/SIMD cap.
// R6: f16-packed ring = 56 VGPRs, no spill, 52.8us. R6 profile: zero-HBM
// dispatches ran at the same speed as 89MB-HBM ones -> latency-bound, and
// occupancy (35%) was grid-capped (16 waves/CU), not register-capped.
// R7: TH=8 -> 4096 blocks -> 32 waves/CU potential; halo work +15% is free.

typedef _Float16 h2 __attribute__((ext_vector_type(2)));

struct GW { unsigned int wh[7]; };   // f16 weight broadcast pairs (lo==hi), SGPR-resident

__device__ __forceinline__ h2 pkrtz(float a, float b) {
    return __builtin_bit_cast(h2, __builtin_amdgcn_cvt_pkrtz(a, b));
}
__device__ __forceinline__ h2 fma2(h2 a, h2 b, h2 c) { return __builtin_elementwise_fma(a, b, c); }

// One input-row stage: load row gy (f32), build s=p+t / d=p-t windows, pack to
// f16 col-pairs, H-blur 4 fields {A=blur(s), B=blur(d), S=blur(s^2), T=blur(d^2)}
// into ring slot SL; when IY>=6 V-blur the ring (packed fma) + SSIM (f32).
template <int SL>
__device__ __forceinline__ void ssim_stage(
    int IY, int oy0, int m, int c0, int clm, int clp,
    const float* __restrict__ pb, const float* __restrict__ tb,
    const h2 (&w2)[7],
    h2 (&ring)[7][8],
    float& acc)
{
    const int gy = oy0 - 3 + IY;
    float pa[12], ta[12];
    if (gy >= 0 && gy < HEI) {
        const float* pr = pb + (size_t)gy * WID;
        const float* tr = tb + (size_t)gy * WID;
        float4 v0 = *(const float4*)(pr + clm);
        float4 v1 = *(const float4*)(pr + c0);
        float4 v2 = *(const float4*)(pr + clp);
        float4 u0 = *(const float4*)(tr + clm);
        float4 u1 = *(const float4*)(tr + c0);
        float4 u2 = *(const float4*)(tr + clp);
        if (m == 0)       { v0 = make_float4(0.f,0.f,0.f,0.f); u0 = make_float4(0.f,0.f,0.f,0.f); }
        if (m == TPB - 1) { v2 = make_float4(0.f,0.f,0.f,0.f); u2 = make_float4(0.f,0.f,0.f,0.f); }
        pa[0]=v0.x; pa[1]=v0.y; pa[2]=v0.z; pa[3]=v0.w;
        pa[4]=v1.x; pa[5]=v1.y; pa[6]=v1.z; pa[7]=v1.w;
        pa[8]=v2.x; pa[9]=v2.y; pa[10]=v2.z; pa[11]=v2.w;
        ta[0]=u0.x; ta[1]=u0.y; ta[2]=u0.z; ta[3]=u0.w;
        ta[4]=u1.x; ta[5]=u1.y; ta[6]=u1.z; ta[7]=u1.w;
        ta[8]=u2.x; ta[9]=u2.y; ta[10]=u2.z; ta[11]=u2.w;
    } else {
#pragma unroll
        for (int k = 0; k < 12; ++k) { pa[k] = 0.f; ta[k] = 0.f; }
    }

    // window value k = column (c0 - 3 + k); output col c uses k = c..c+6
    float ws[10], wd[10];
#pragma unroll
    for (int k = 0; k < 10; ++k) {
        ws[k] = pa[k + 1] + ta[k + 1];
        wd[k] = pa[k + 1] - ta[k + 1];
    }

    h2 W[9];   // packed sliding pairs W[k] = (w[k], w[k+1]); col-pair cp uses W[2cp..2cp+6]

    // field A = blur(s)
#pragma unroll
    for (int k = 0; k < 9; ++k) W[k] = pkrtz(ws[k], ws[k + 1]);
#pragma unroll
    for (int cp = 0; cp < 2; ++cp) {
        h2 a = w2[0] * W[2 * cp];
#pragma unroll
        for (int i = 1; i < 7; ++i) a = fma2(w2[i], W[2 * cp + i], a);
        ring[SL][0 + cp] = a;
    }
    // field S = blur(s^2)
#pragma unroll
    for (int k = 0; k < 9; ++k) W[k] = W[k] * W[k];
#pragma unroll
    for (int cp = 0; cp < 2; ++cp) {
        h2 a = w2[0] * W[2 * cp];
#pragma unroll
        for (int i = 1; i < 7; ++i) a = fma2(w2[i], W[2 * cp + i], a);
        ring[SL][4 + cp] = a;
    }
    // field B = blur(d)
#pragma unroll
    for (int k = 0; k < 9; ++k) W[k] = pkrtz(wd[k], wd[k + 1]);
#pragma unroll
    for (int cp = 0; cp < 2; ++cp) {
        h2 a = w2[0] * W[2 * cp];
#pragma unroll
        for (int i = 1; i < 7; ++i) a = fma2(w2[i], W[2 * cp + i], a);
        ring[SL][2 + cp] = a;
    }
    // field T = blur(d^2)
#pragma unroll
    for (int k = 0; k < 9; ++k) W[k] = W[k] * W[k];
#pragma unroll
    for (int cp = 0; cp < 2; ++cp) {
        h2 a = w2[0] * W[2 * cp];
#pragma unroll
        for (int i = 1; i < 7; ++i) a = fma2(w2[i], W[2 * cp + i], a);
        ring[SL][6 + cp] = a;
    }

    if (IY >= 6) {
        const float C1 = 1e-4f, C2 = 9e-4f;
#pragma unroll
        for (int cp = 0; cp < 2; ++cp) {
            h2 vA = w2[0] * ring[(SL + 1) % 7][0 + cp];
            h2 vB = w2[0] * ring[(SL + 1) % 7][2 + cp];
            h2 vS = w2[0] * ring[(SL + 1) % 7][4 + cp];
            h2 vT = w2[0] * ring[(SL + 1) % 7][6 + cp];
#pragma unroll
            for (int j = 1; j < 7; ++j) {
                const int sl = (SL + 1 + j) % 7;   // compile-time
                vA = fma2(w2[j], ring[sl][0 + cp], vA);
                vB = fma2(w2[j], ring[sl][2 + cp], vB);
                vS = fma2(w2[j], ring[sl][4 + cp], vS);
                vT = fma2(w2[j], ring[sl][6 + cp], vT);
            }
#pragma unroll
            for (int e = 0; e < 2; ++e) {
                const float fA = (float)vA[e], fB = (float)vB[e];
                const float fS = (float)vS[e], fT = (float)vT[e];
                const float A2 = fA * fA, B2 = fB * fB;
                const float muct2 = 0.5f * (A2 - B2);   // 2*mu_p*mu_t
                const float muss  = 0.5f * (A2 + B2);   // mu_p^2 + mu_t^2
                const float ptb2  = 0.5f * (fS - fT);   // 2*blur(p*t)
                const float ssb   = 0.5f * (fS + fT);   // blur(p^2 + t^2)
                const float num = (muct2 + C1) * (ptb2 - muct2 + C2);
                const float den = (muss + C1) * (ssb - muss + C2);
                acc += num * __builtin_amdgcn_rcpf(den);
            }
        }
    }
}

__global__ __launch_bounds__(TPB, 8)
void ssim_main_k(const float* __restrict__ pred,
                 const float* __restrict__ targ,
                 float* __restrict__ partial,   // NBLK floats (d_ws), or null
                 float* __restrict__ outacc,    // fallback atomic accumulator
                 GW gw)
{
    const int m    = threadIdx.x;
    const int bid  = blockIdx.x;
    const int img  = bid >> 6;            // NTILE == 64
    const int tile = bid & (NTILE - 1);
    const int oy0  = tile * TH;

    h2 w2[7];
#pragma unroll
    for (int j = 0; j < 7; ++j) w2[j] = __builtin_bit_cast(h2, gw.wh[j]);

    const size_t ioff = (size_t)img * (WID * HEI);
    const float* pb = pred + ioff;
    const float* tb = targ + ioff;

    const int c0  = 4 * m;
    const int clm = (m == 0) ? 0 : (c0 - 4);          // clamped (value zeroed)
    const int clp = (m == TPB - 1) ? c0 : (c0 + 4);   // clamped (value zeroed)

    h2 ring[7][8];   // [slot][field*2 + colpair]; fields A,B,S,T
    float acc = 0.f;

    // 14 input rows = 2*7; groups of 7 so ring slot == IY % 7 is static
    for (int it = 0; it < 2; ++it) {
        const int base = it * 7;
        ssim_stage<0>(base + 0, oy0, m, c0, clm, clp, pb, tb, w2, ring, acc);
        ssim_stage<1>(base + 1, oy0, m, c0, clm, clp, pb, tb, w2, ring, acc);
        ssim_stage<2>(base + 2, oy0, m, c0, clm, clp, pb, tb, w2, ring, acc);
        ssim_stage<3>(base + 3, oy0, m, c0, clm, clp, pb, tb, w2, ring, acc);
        ssim_stage<4>(base + 4, oy0, m, c0, clm, clp, pb, tb, w2, ring, acc);
        ssim_stage<5>(base + 5, oy0, m, c0, clm, clp, pb, tb, w2, ring, acc);
        ssim_stage<6>(base + 6, oy0, m, c0, clm, clp, pb, tb, w2, ring, acc);
    }

    // block reduction: wave shfl tree, then cross-wave via LDS
#pragma unroll
    for (int off = 32; off > 0; off >>= 1)
        acc += __shfl_down(acc, off, 64);
    __shared__ float wpart[TPB / 64];
    if ((m & 63) == 0) wpart[m >> 6] = acc;
    __syncthreads();
    if (m == 0) {
        const float tot = wpart[0] + wpart[1];
        if (partial) partial[bid] = tot;
        else atomicAdd(outacc, tot);
    }
}

__global__ void ssim_finalize_k(const float* __restrict__ partial,
                                float* __restrict__ out, int usews)
{
    const float invN = 1.0f / (float)((size_t)NIMG * WID * HEI);
    if (usews) {
        float s = 0.f;
        for (int i = threadIdx.x; i < NBLK; i += 256) s += partial[i];
#pragma unroll
        for (int off = 32; off > 0; off >>= 1) s += __shfl_down(s, off, 64);
        __shared__ float wp[4];
        if ((threadIdx.x & 63) == 0) wp[threadIdx.x >> 6] = s;
        __syncthreads();
        if (threadIdx.x == 0) out[0] = 1.0f - (wp[0] + wp[1] + wp[2] + wp[3]) * invN;
    } else {
        if (threadIdx.x == 0) out[0] = 1.0f - out[0] * invN;
    }
}

// host f32 -> f16 bits, round-to-nearest-even (weights are normal, positive)
static unsigned short f32_to_f16(float f) {
    union { float f; unsigned int u; } c; c.f = f;
    const unsigned int u = c.u;
    const int exp = (int)((u >> 23) & 0xFF) - 127 + 15;
    const unsigned int man = u & 0x7FFFFFu;
    if (exp <= 0) return 0;
    unsigned int base = ((unsigned int)exp << 10) | (man >> 13);
    const unsigned int rem = man & 0x1FFFu;
    base += (rem > 0x1000u) || (rem == 0x1000u && (base & 1u));
    return (unsigned short)base;
}
static float f16_to_f32(unsigned short h) {
    const int exp = (h >> 10) & 0x1F;
    const unsigned int man = h & 0x3FFu;
    if (exp == 0) return 0.f;
    union { unsigned int u; float f; } c;
    c.u = ((unsigned int)(exp - 15 + 127) << 23) | (man << 13);
    return c.f;
}

extern "C" void kernel_launch(void* const* d_in, const int* in_sizes, int n_in,
                              void* d_out, int out_size, void* d_ws, size_t ws_size,
                              hipStream_t stream)
{
    const float* pred = (const float*)d_in[0];
    const float* targ = (const float*)d_in[1];
    float* out = (float*)d_out;

    GW gw;
    {
        double g[7], s = 0.0;
        for (int i = 0; i < 7; ++i) {
            const double c = (double)(i - 3);
            g[i] = exp(-c * c / (2.0 * 1.5 * 1.5));
            s += g[i];
        }
        unsigned short h16[7];
        for (int i = 0; i < 7; ++i) h16[i] = f32_to_f16((float)(g[i] / s));
        // renormalize so the f16 weights sum as close to 1.0 as representable:
        // center tap = round_f16(1 - sum(others)) kills the systematic bias.
        float so = 0.f;
        for (int i = 0; i < 7; ++i) if (i != 3) so += f16_to_f32(h16[i]);
        h16[3] = f32_to_f16(1.0f - so);
        for (int i = 0; i < 7; ++i)
            gw.wh[i] = (unsigned int)h16[i] | ((unsigned int)h16[i] << 16);
    }

    const bool usews = (ws_size >= NBLK * sizeof(float));
    float* partial = usews ? (float*)d_ws : nullptr;
    if (!usews) (void)hipMemsetAsync(d_out, 0, sizeof(float), stream);

    ssim_main_k<<<NBLK, TPB, 0, stream>>>(pred, targ, partial, out, gw);
    ssim_finalize_k<<<1, 256, 0, stream>>>(partial, out, usews ? 1 : 0);
}

// Round 8
// 60.080 us; speedup vs baseline: 1.5637x; 1.5637x over previous
//
#include <hip/hip_runtime.h>
#include <cmath>

#define TPB   128                 // threads per block (2 waves); each thread owns 4 cols
#define TH    8                   // output rows per block tile (14 input rows = 2*7)
#define WID   512
#define HEI   512
#define NIMG  64
#define NTILE (HEI / TH)          // 64
#define NBLK  (NIMG * NTILE)      // 4096

// R4: f32 ring -> ~200 regs -> 2 waves/SIMD cap. R6: f16 ring = 56 VGPR,
// 52.8us, occupancy grid-capped at 35%. R7: TH=8 grid filled the machine
// (81% occ) BUT __launch_bounds__(128,8) forced allocator to 32 VGPR ->
// 80MB spill -> 93.9us. R8: keep the 4096-block grid, relax the bound to
// (128,4): allocator returns to ~56 VGPR (<=64 -> HW allows 8 waves/SIMD
// anyway), grid supplies 32 waves/CU. Never force launch_bounds tighter
// than the natural allocation.

typedef _Float16 h2 __attribute__((ext_vector_type(2)));

struct GW { unsigned int wh[7]; };   // f16 weight broadcast pairs (lo==hi), SGPR-resident

__device__ __forceinline__ h2 pkrtz(float a, float b) {
    return __builtin_bit_cast(h2, __builtin_amdgcn_cvt_pkrtz(a, b));
}
__device__ __forceinline__ h2 fma2(h2 a, h2 b, h2 c) { return __builtin_elementwise_fma(a, b, c); }

// One input-row stage: load row gy (f32), build s=p+t / d=p-t windows, pack to
// f16 col-pairs, H-blur 4 fields {A=blur(s), B=blur(d), S=blur(s^2), T=blur(d^2)}
// into ring slot SL; when IY>=6 V-blur the ring (packed fma) + SSIM (f32).
template <int SL>
__device__ __forceinline__ void ssim_stage(
    int IY, int oy0, int m, int c0, int clm, int clp,
    const float* __restrict__ pb, const float* __restrict__ tb,
    const h2 (&w2)[7],
    h2 (&ring)[7][8],
    float& acc)
{
    const int gy = oy0 - 3 + IY;
    float pa[12], ta[12];
    if (gy >= 0 && gy < HEI) {
        const float* pr = pb + (size_t)gy * WID;
        const float* tr = tb + (size_t)gy * WID;
        float4 v0 = *(const float4*)(pr + clm);
        float4 v1 = *(const float4*)(pr + c0);
        float4 v2 = *(const float4*)(pr + clp);
        float4 u0 = *(const float4*)(tr + clm);
        float4 u1 = *(const float4*)(tr + c0);
        float4 u2 = *(const float4*)(tr + clp);
        if (m == 0)       { v0 = make_float4(0.f,0.f,0.f,0.f); u0 = make_float4(0.f,0.f,0.f,0.f); }
        if (m == TPB - 1) { v2 = make_float4(0.f,0.f,0.f,0.f); u2 = make_float4(0.f,0.f,0.f,0.f); }
        pa[0]=v0.x; pa[1]=v0.y; pa[2]=v0.z; pa[3]=v0.w;
        pa[4]=v1.x; pa[5]=v1.y; pa[6]=v1.z; pa[7]=v1.w;
        pa[8]=v2.x; pa[9]=v2.y; pa[10]=v2.z; pa[11]=v2.w;
        ta[0]=u0.x; ta[1]=u0.y; ta[2]=u0.z; ta[3]=u0.w;
        ta[4]=u1.x; ta[5]=u1.y; ta[6]=u1.z; ta[7]=u1.w;
        ta[8]=u2.x; ta[9]=u2.y; ta[10]=u2.z; ta[11]=u2.w;
    } else {
#pragma unroll
        for (int k = 0; k < 12; ++k) { pa[k] = 0.f; ta[k] = 0.f; }
    }

    // window value k = column (c0 - 3 + k); output col c uses k = c..c+6
    float ws[10], wd[10];
#pragma unroll
    for (int k = 0; k < 10; ++k) {
        ws[k] = pa[k + 1] + ta[k + 1];
        wd[k] = pa[k + 1] - ta[k + 1];
    }

    h2 W[9];   // packed sliding pairs W[k] = (w[k], w[k+1]); col-pair cp uses W[2cp..2cp+6]

    // field A = blur(s)
#pragma unroll
    for (int k = 0; k < 9; ++k) W[k] = pkrtz(ws[k], ws[k + 1]);
#pragma unroll
    for (int cp = 0; cp < 2; ++cp) {
        h2 a = w2[0] * W[2 * cp];
#pragma unroll
        for (int i = 1; i < 7; ++i) a = fma2(w2[i], W[2 * cp + i], a);
        ring[SL][0 + cp] = a;
    }
    // field S = blur(s^2)
#pragma unroll
    for (int k = 0; k < 9; ++k) W[k] = W[k] * W[k];
#pragma unroll
    for (int cp = 0; cp < 2; ++cp) {
        h2 a = w2[0] * W[2 * cp];
#pragma unroll
        for (int i = 1; i < 7; ++i) a = fma2(w2[i], W[2 * cp + i], a);
        ring[SL][4 + cp] = a;
    }
    // field B = blur(d)
#pragma unroll
    for (int k = 0; k < 9; ++k) W[k] = pkrtz(wd[k], wd[k + 1]);
#pragma unroll
    for (int cp = 0; cp < 2; ++cp) {
        h2 a = w2[0] * W[2 * cp];
#pragma unroll
        for (int i = 1; i < 7; ++i) a = fma2(w2[i], W[2 * cp + i], a);
        ring[SL][2 + cp] = a;
    }
    // field T = blur(d^2)
#pragma unroll
    for (int k = 0; k < 9; ++k) W[k] = W[k] * W[k];
#pragma unroll
    for (int cp = 0; cp < 2; ++cp) {
        h2 a = w2[0] * W[2 * cp];
#pragma unroll
        for (int i = 1; i < 7; ++i) a = fma2(w2[i], W[2 * cp + i], a);
        ring[SL][6 + cp] = a;
    }

    if (IY >= 6) {
        const float C1 = 1e-4f, C2 = 9e-4f;
#pragma unroll
        for (int cp = 0; cp < 2; ++cp) {
            h2 vA = w2[0] * ring[(SL + 1) % 7][0 + cp];
            h2 vB = w2[0] * ring[(SL + 1) % 7][2 + cp];
            h2 vS = w2[0] * ring[(SL + 1) % 7][4 + cp];
            h2 vT = w2[0] * ring[(SL + 1) % 7][6 + cp];
#pragma unroll
            for (int j = 1; j < 7; ++j) {
                const int sl = (SL + 1 + j) % 7;   // compile-time
                vA = fma2(w2[j], ring[sl][0 + cp], vA);
                vB = fma2(w2[j], ring[sl][2 + cp], vB);
                vS = fma2(w2[j], ring[sl][4 + cp], vS);
                vT = fma2(w2[j], ring[sl][6 + cp], vT);
            }
#pragma unroll
            for (int e = 0; e < 2; ++e) {
                const float fA = (float)vA[e], fB = (float)vB[e];
                const float fS = (float)vS[e], fT = (float)vT[e];
                const float A2 = fA * fA, B2 = fB * fB;
                const float muct2 = 0.5f * (A2 - B2);   // 2*mu_p*mu_t
                const float muss  = 0.5f * (A2 + B2);   // mu_p^2 + mu_t^2
                const float ptb2  = 0.5f * (fS - fT);   // 2*blur(p*t)
                const float ssb   = 0.5f * (fS + fT);   // blur(p^2 + t^2)
                const float num = (muct2 + C1) * (ptb2 - muct2 + C2);
                const float den = (muss + C1) * (ssb - muss + C2);
                acc += num * __builtin_amdgcn_rcpf(den);
            }
        }
    }
}

__global__ __launch_bounds__(TPB, 4)
void ssim_main_k(const float* __restrict__ pred,
                 const float* __restrict__ targ,
                 float* __restrict__ partial,   // NBLK floats (d_ws), or null
                 float* __restrict__ outacc,    // fallback atomic accumulator
                 GW gw)
{
    const int m    = threadIdx.x;
    const int bid  = blockIdx.x;
    const int img  = bid >> 6;            // NTILE == 64
    const int tile = bid & (NTILE - 1);
    const int oy0  = tile * TH;

    h2 w2[7];
#pragma unroll
    for (int j = 0; j < 7; ++j) w2[j] = __builtin_bit_cast(h2, gw.wh[j]);

    const size_t ioff = (size_t)img * (WID * HEI);
    const float* pb = pred + ioff;
    const float* tb = targ + ioff;

    const int c0  = 4 * m;
    const int clm = (m == 0) ? 0 : (c0 - 4);          // clamped (value zeroed)
    const int clp = (m == TPB - 1) ? c0 : (c0 + 4);   // clamped (value zeroed)

    h2 ring[7][8];   // [slot][field*2 + colpair]; fields A,B,S,T
    float acc = 0.f;

    // 14 input rows = 2*7; groups of 7 so ring slot == IY % 7 is static
    for (int it = 0; it < 2; ++it) {
        const int base = it * 7;
        ssim_stage<0>(base + 0, oy0, m, c0, clm, clp, pb, tb, w2, ring, acc);
        ssim_stage<1>(base + 1, oy0, m, c0, clm, clp, pb, tb, w2, ring, acc);
        ssim_stage<2>(base + 2, oy0, m, c0, clm, clp, pb, tb, w2, ring, acc);
        ssim_stage<3>(base + 3, oy0, m, c0, clm, clp, pb, tb, w2, ring, acc);
        ssim_stage<4>(base + 4, oy0, m, c0, clm, clp, pb, tb, w2, ring, acc);
        ssim_stage<5>(base + 5, oy0, m, c0, clm, clp, pb, tb, w2, ring, acc);
        ssim_stage<6>(base + 6, oy0, m, c0, clm, clp, pb, tb, w2, ring, acc);
    }

    // block reduction: wave shfl tree, then cross-wave via LDS
#pragma unroll
    for (int off = 32; off > 0; off >>= 1)
        acc += __shfl_down(acc, off, 64);
    __shared__ float wpart[TPB / 64];
    if ((m & 63) == 0) wpart[m >> 6] = acc;
    __syncthreads();
    if (m == 0) {
        const float tot = wpart[0] + wpart[1];
        if (partial) partial[bid] = tot;
        else atomicAdd(outacc, tot);
    }
}

__global__ void ssim_finalize_k(const float* __restrict__ partial,
                                float* __restrict__ out, int usews)
{
    const float invN = 1.0f / (float)((size_t)NIMG * WID * HEI);
    if (usews) {
        float s = 0.f;
        for (int i = threadIdx.x; i < NBLK; i += 256) s += partial[i];
#pragma unroll
        for (int off = 32; off > 0; off >>= 1) s += __shfl_down(s, off, 64);
        __shared__ float wp[4];
        if ((threadIdx.x & 63) == 0) wp[threadIdx.x >> 6] = s;
        __syncthreads();
        if (threadIdx.x == 0) out[0] = 1.0f - (wp[0] + wp[1] + wp[2] + wp[3]) * invN;
    } else {
        if (threadIdx.x == 0) out[0] = 1.0f - out[0] * invN;
    }
}

// host f32 -> f16 bits, round-to-nearest-even (weights are normal, positive)
static unsigned short f32_to_f16(float f) {
    union { float f; unsigned int u; } c; c.f = f;
    const unsigned int u = c.u;
    const int exp = (int)((u >> 23) & 0xFF) - 127 + 15;
    const unsigned int man = u & 0x7FFFFFu;
    if (exp <= 0) return 0;
    unsigned int base = ((unsigned int)exp << 10) | (man >> 13);
    const unsigned int rem = man & 0x1FFFu;
    base += (rem > 0x1000u) || (rem == 0x1000u && (base & 1u));
    return (unsigned short)base;
}
static float f16_to_f32(unsigned short h) {
    const int exp = (h >> 10) & 0x1F;
    const unsigned int man = h & 0x3FFu;
    if (exp == 0) return 0.f;
    union { unsigned int u; float f; } c;
    c.u = ((unsigned int)(exp - 15 + 127) << 23) | (man << 13);
    return c.f;
}

extern "C" void kernel_launch(void* const* d_in, const int* in_sizes, int n_in,
                              void* d_out, int out_size, void* d_ws, size_t ws_size,
                              hipStream_t stream)
{
    const float* pred = (const float*)d_in[0];
    const float* targ = (const float*)d_in[1];
    float* out = (float*)d_out;

    GW gw;
    {
        double g[7], s = 0.0;
        for (int i = 0; i < 7; ++i) {
            const double c = (double)(i - 3);
            g[i] = exp(-c * c / (2.0 * 1.5 * 1.5));
            s += g[i];
        }
        unsigned short h16[7];
        for (int i = 0; i < 7; ++i) h16[i] = f32_to_f16((float)(g[i] / s));
        // renormalize so the f16 weights sum as close to 1.0 as representable:
        // center tap = round_f16(1 - sum(others)) kills the systematic bias.
        float so = 0.f;
        for (int i = 0; i < 7; ++i) if (i != 3) so += f16_to_f32(h16[i]);
        h16[3] = f32_to_f16(1.0f - so);
        for (int i = 0; i < 7; ++i)
            gw.wh[i] = (unsigned int)h16[i] | ((unsigned int)h16[i] << 16);
    }

    const bool usews = (ws_size >= NBLK * sizeof(float));
    float* partial = usews ? (float*)d_ws : nullptr;
    if (!usews) (void)hipMemsetAsync(d_out, 0, sizeof(float), stream);

    ssim_main_k<<<NBLK, TPB, 0, stream>>>(pred, targ, partial, out, gw);
    ssim_finalize_k<<<1, 256, 0, stream>>>(partial, out, usews ? 1 : 0);
}